// Round 13
// baseline (55.473 us; speedup 1.0000x reference)
//
#include <hip/hip_runtime.h>
#include <hip/hip_bf16.h>
#include <hip/hip_fp16.h>

// Problem constants
#define D1   128
#define NQ   2048
#define NP   256
#define H1   128
#define H2   64

typedef __attribute__((ext_vector_type(8))) _Float16 f16x8;
typedef __attribute__((ext_vector_type(2))) __fp16   h16x2;
typedef __attribute__((ext_vector_type(4))) float    f32x4;

static __device__ __forceinline__ f16x8 cvt8(float4 a, float4 b) {
    f16x8 f;
    f[0] = (_Float16)a.x; f[1] = (_Float16)a.y;
    f[2] = (_Float16)a.z; f[3] = (_Float16)a.w;
    f[4] = (_Float16)b.x; f[5] = (_Float16)b.y;
    f[6] = (_Float16)b.z; f[7] = (_Float16)b.w;
    return f;
}
static __device__ __forceinline__ float sq8(float4 a, float4 b) {
    return a.x*a.x + a.y*a.y + a.z*a.z + a.w*a.w
         + b.x*b.x + b.y*b.y + b.z*b.z + b.w*b.w;
}

// ---------------------------------------------------------------------------
// ONE kernel. 512 threads, grid 256 (1 block/CU). Block owns 8 q x 256 p.
// Wave w: p-range (w&3)*64, q-half & h-tile-half (w>>2).
//
// Phase 0: stage W1p (f32->f16, XOR-swizzled) into LDS coalesced; load into
//   regs: Praw (own 64 p as B-frags, f16) + psq, dist-A q rows + asq,
//   q-proj A/B frags, Af (W2) frags.
// Phase 1: q-proj (D[h][q], 4 MFMA) -> qh_s (b1 folded, packed b64 writes);
//   dist (D[q][p], 16 MFMA) -> bse[4] in regs (R10 extraction);
//   p-proj (D[h][p] = mfma(W1p-rows, Praw), 64 MFMA) -> ph_s: C row=h is
//   contiguous in reg -> cvt_pkrtz pairs -> ds_write_b64, XOR-swizzled.
// Phase 2: R12 main loop: P-frags from ph_s (swizzled 16B reads), Af in
//   regs, qk broadcast from qh_s; packed-f16 epilogue; fast softplus;
//   out = bse * (1+softplus(z)).
// ---------------------------------------------------------------------------
__global__ void __launch_bounds__(512, 2)
fused_kernel(const float* __restrict__ q, const float* __restrict__ p,
             const float* __restrict__ W1, const float* __restrict__ b1,
             const float* __restrict__ W2, const float* __restrict__ b2,
             const float* __restrict__ w3, const float* __restrict__ b3,
             float* __restrict__ out) {
    extern __shared__ char lds[];
    char* w1p_s = lds;                       // 32768 B  [h][d] f16 swizzled
    char* ph_s  = lds + 32768;               // 65536 B  [p][h] f16 swizzled
    _Float16* qh_s = (_Float16*)(lds + 32768 + 65536);   // [8][128] f16 linear

    int tid = threadIdx.x, lane = tid & 63, w = tid >> 6;   // w 0..7
    int lo = lane & 15, g = lane >> 4;
    int wp = w & 3;              // p-range
    int qh2 = w >> 2;            // q-half / h-tile-half
    int q0 = blockIdx.x * 8;

    // ---------------- phase 0 ----------------
    // stage W1p = W1[:,128:256] as f16 [128][128], swizzle byte ^= (h&7)<<4
    #pragma unroll
    for (int it = 0; it < 4; ++it) {
        int j8 = (it * 512 + tid) * 8;       // f16 element index (8 per thread)
        int h = j8 >> 7, d = j8 & 127;
        const float* src = W1 + h * (2 * D1) + D1 + d;
        float4 a = *(const float4*)src, b = *(const float4*)(src + 4);
        *(f16x8*)(w1p_s + ((j8 * 2) ^ ((h & 7) << 4))) = cvt8(a, b);
    }

    // Praw: own 64 p rows as B-frags (col=p, k=d) + psq (f32-sourced norms)
    f16x8 Praw[4][4];
    float psq[4];
    #pragma unroll
    for (int n = 0; n < 4; ++n) {
        int prow = wp * 64 + n * 16 + lo;
        psq[n] = 0.f;
        #pragma unroll
        for (int ks = 0; ks < 4; ++ks) {
            const float* src = p + prow * D1 + ks * 32 + g * 8;
            float4 a = *(const float4*)src, b = *(const float4*)(src + 4);
            psq[n] += sq8(a, b);
            Praw[n][ks] = cvt8(a, b);
        }
        psq[n] += __shfl_xor(psq[n], 16);
        psq[n] += __shfl_xor(psq[n], 32);    // pn[prow] on every lane
    }

    // dist A-frags: q rows q0 + qh2*4 + (lo&3)  (rows duplicate, R10 trick)
    f16x8 Adist[4];
    float asq = 0.f;
    {
        int qrow = q0 + qh2 * 4 + (lo & 3);
        #pragma unroll
        for (int ks = 0; ks < 4; ++ks) {
            const float* src = q + qrow * D1 + ks * 32 + g * 8;
            float4 a = *(const float4*)src, b = *(const float4*)(src + 4);
            asq += sq8(a, b);
            Adist[ks] = cvt8(a, b);
        }
        asq += __shfl_xor(asq, 16);
        asq += __shfl_xor(asq, 32);          // qn[qrow] on every lane
    }

    // q-proj operands: A = W1q rows (w*16+lo); B = q^T cols (lo&7)
    f16x8 Aq[4], Bq[4];
    {
        int qrow2 = q0 + (lo & 7);
        #pragma unroll
        for (int ks = 0; ks < 4; ++ks) {
            const float* sa = W1 + (w * 16 + lo) * (2 * D1) + ks * 32 + g * 8;
            Aq[ks] = cvt8(*(const float4*)sa, *(const float4*)(sa + 4));
            const float* sb = q + qrow2 * D1 + ks * 32 + g * 8;
            Bq[ks] = cvt8(*(const float4*)sb, *(const float4*)(sb + 4));
        }
    }

    // Af (W2) frags: issued now, consumed in phase 2
    f16x8 Af[4][4];
    #pragma unroll
    for (int m = 0; m < 4; ++m)
        #pragma unroll
        for (int ks = 0; ks < 4; ++ks) {
            const float* src = W2 + (m * 16 + lo) * H1 + ks * 32 + g * 8;
            Af[m][ks] = cvt8(*(const float4*)src, *(const float4*)(src + 4));
            asm volatile("" : "+v"(Af[m][ks]));
        }

    float4 b1v = *(const float4*)(b1 + w * 16 + g * 4);
    const f32x4 Zv = (f32x4){0.f, 0.f, 0.f, 0.f};
    const f16x8 zz = {};
    const h16x2 z2 = {};
    __syncthreads();   // w1p_s ready

    // ---------------- phase 1 ----------------
    // q-proj: D[h=w*16+g*4+r][q=lo] ; write qh_s rows lo<8, b1 folded
    {
        f32x4 Cq = Zv;
        #pragma unroll
        for (int ks = 0; ks < 4; ++ks)
            Cq = __builtin_amdgcn_mfma_f32_16x16x32_f16(Aq[ks], Bq[ks], Cq, 0, 0, 0);
        if (lo < 8) {
            union { h16x2 h[2]; uint2 v; } pk;
            pk.h[0] = __builtin_amdgcn_cvt_pkrtz(Cq[0] + b1v.x, Cq[1] + b1v.y);
            pk.h[1] = __builtin_amdgcn_cvt_pkrtz(Cq[2] + b1v.z, Cq[3] + b1v.w);
            *(uint2*)((char*)qh_s + lo * 256 + w * 32 + g * 8) = pk.v;
        }
    }

    // dist: D[q][p] -> bse[qq] (R10 extraction)
    float bse[4];
    {
        f32x4 Cd[4];
        #pragma unroll
        for (int n = 0; n < 4; ++n) {
            Cd[n] = Zv;
            #pragma unroll
            for (int ks = 0; ks < 4; ++ks)
                Cd[n] = __builtin_amdgcn_mfma_f32_16x16x32_f16(Adist[ks], Praw[n][ks], Cd[n], 0, 0, 0);
        }
        float pnm = (g == 0) ? psq[0] : (g == 1) ? psq[1] : (g == 2) ? psq[2] : psq[3];
        #pragma unroll
        for (int qq = 0; qq < 4; ++qq) {
            float qn = __shfl(asq, qq);      // lane qq holds row q0+qh2*4+qq
            float dg = (g == 0) ? Cd[0][qq] : (g == 1) ? Cd[1][qq]
                     : (g == 2) ? Cd[2][qq] : Cd[3][qq];
            bse[qq] = fmaxf(qn + pnm - 2.f * dg, 0.f);
        }
    }

    // p-proj: wave w covers h-tiles qh2*4 .. qh2*4+3 x own 4 p-tiles
    #pragma unroll
    for (int hp = 0; hp < 2; ++hp) {
        f16x8 Ap[2][4];
        #pragma unroll
        for (int ht = 0; ht < 2; ++ht)
            #pragma unroll
            for (int ks = 0; ks < 4; ++ks) {
                int h = (qh2 * 4 + hp * 2 + ht) * 16 + lo;
                Ap[ht][ks] = *(const f16x8*)(w1p_s +
                    ((h * 256 + ks * 64 + g * 16) ^ ((h & 7) << 4)));
            }
        #pragma unroll
        for (int n = 0; n < 4; ++n) {
            f32x4 Cp0 = Zv, Cp1 = Zv;
            #pragma unroll
            for (int ks = 0; ks < 4; ++ks) {
                Cp0 = __builtin_amdgcn_mfma_f32_16x16x32_f16(Ap[0][ks], Praw[n][ks], Cp0, 0, 0, 0);
                Cp1 = __builtin_amdgcn_mfma_f32_16x16x32_f16(Ap[1][ks], Praw[n][ks], Cp1, 0, 0, 0);
            }
            int pp = wp * 64 + n * 16 + lo;
            #pragma unroll
            for (int ht = 0; ht < 2; ++ht) {
                f32x4 Cp = ht ? Cp1 : Cp0;
                int h0 = (qh2 * 4 + hp * 2 + ht) * 16 + g * 4;
                union { h16x2 h[2]; uint2 v; } pk;
                pk.h[0] = __builtin_amdgcn_cvt_pkrtz(Cp[0], Cp[1]);
                pk.h[1] = __builtin_amdgcn_cvt_pkrtz(Cp[2], Cp[3]);
                *(uint2*)(ph_s + ((pp * 256 + h0 * 2) ^ ((pp & 7) << 4))) = pk.v;
            }
        }
    }
    __syncthreads();   // ph_s, qh_s ready

    // ---------------- phase 2: main loop (R12 body) ----------------
    f16x8 P[4][4];
    #pragma unroll
    for (int n = 0; n < 4; ++n)
        #pragma unroll
        for (int ks = 0; ks < 4; ++ks) {
            int pp = wp * 64 + n * 16 + lo;
            P[n][ks] = *(const f16x8*)(ph_s +
                ((pp * 256 + ks * 64 + g * 16) ^ ((pp & 7) << 4)));
            asm volatile("" : "+v"(P[n][ks]));
        }

    h16x2 b2p[4][2], w3p[4][2];
    #pragma unroll
    for (int m = 0; m < 4; ++m) {
        float4 bb = *(const float4*)(b2 + m * 16 + g * 4);
        float4 ww = *(const float4*)(w3 + m * 16 + g * 4);
        b2p[m][0] = __builtin_amdgcn_cvt_pkrtz(bb.x, bb.y);
        b2p[m][1] = __builtin_amdgcn_cvt_pkrtz(bb.z, bb.w);
        w3p[m][0] = __builtin_amdgcn_cvt_pkrtz(ww.x, ww.y);
        w3p[m][1] = __builtin_amdgcn_cvt_pkrtz(ww.z, ww.w);
    }
    float b3v = b3[0];
    int pmine = wp * 64 + lane;
    int qb = qh2 * 4;

    f16x8 qkr[2][4];
    #pragma unroll
    for (int ks = 0; ks < 4; ++ks)
        qkr[0][ks] = *(const f16x8*)(qh_s + qb * H1 + ks * 32 + g * 8);

    #pragma unroll
    for (int qq = 0; qq < 4; ++qq) {
        float zp[4];
        #pragma unroll
        for (int hh = 0; hh < 2; ++hh) {
            f32x4 C[4][2];
            #pragma unroll
            for (int ks = 0; ks < 4; ++ks) {
                f16x8 B0 = __builtin_elementwise_max(P[2 * hh + 0][ks] + qkr[qq & 1][ks], zz);
                f16x8 B1 = __builtin_elementwise_max(P[2 * hh + 1][ks] + qkr[qq & 1][ks], zz);
                #pragma unroll
                for (int m = 0; m < 4; ++m) {
                    if (ks == 0) {
                        C[m][0] = __builtin_amdgcn_mfma_f32_16x16x32_f16(Af[m][0], B0, Zv, 0, 0, 0);
                        C[m][1] = __builtin_amdgcn_mfma_f32_16x16x32_f16(Af[m][0], B1, Zv, 0, 0, 0);
                    } else {
                        C[m][0] = __builtin_amdgcn_mfma_f32_16x16x32_f16(Af[m][ks], B0, C[m][0], 0, 0, 0);
                        C[m][1] = __builtin_amdgcn_mfma_f32_16x16x32_f16(Af[m][ks], B1, C[m][1], 0, 0, 0);
                    }
                }
            }
            if (hh == 0 && qq + 1 < 4) {
                #pragma unroll
                for (int ks = 0; ks < 4; ++ks)
                    qkr[(qq + 1) & 1][ks] =
                        *(const f16x8*)(qh_s + (qb + qq + 1) * H1 + ks * 32 + g * 8);
            }
            #pragma unroll
            for (int n2 = 0; n2 < 2; ++n2) {
                float sA = 0.f, sB = 0.f;
                #pragma unroll
                for (int m = 0; m < 4; ++m) {
                    h16x2 c01 = __builtin_amdgcn_cvt_pkrtz(C[m][n2][0], C[m][n2][1]);
                    h16x2 c23 = __builtin_amdgcn_cvt_pkrtz(C[m][n2][2], C[m][n2][3]);
                    h16x2 h01 = __builtin_elementwise_max(c01 + b2p[m][0], z2);
                    h16x2 h23 = __builtin_elementwise_max(c23 + b2p[m][1], z2);
                    sA = __builtin_amdgcn_fdot2(h01, w3p[m][0], sA, false);
                    sB = __builtin_amdgcn_fdot2(h23, w3p[m][1], sB, false);
                }
                zp[2 * hh + n2] = sA + sB;
            }
        }
        float sh[4];
        #pragma unroll
        for (int i = 0; i < 4; ++i) sh[i] = __shfl_xor(zp[i], 16);
        #pragma unroll
        for (int i = 0; i < 4; ++i) zp[i] += sh[i];
        #pragma unroll
        for (int i = 0; i < 4; ++i) sh[i] = __shfl_xor(zp[i], 32);
        #pragma unroll
        for (int i = 0; i < 4; ++i) zp[i] += sh[i];

        float z = (g == 0) ? zp[0] : (g == 1) ? zp[1] : (g == 2) ? zp[2] : zp[3];
        z += b3v;
        float sp = fmaxf(z, 0.f) + __logf(1.f + __expf(-fabsf(z)));
        out[(q0 + qb + qq) * NP + pmine] = bse[qq] * (1.f + sp);   // cw ~= alpha
    }
}

extern "C" void kernel_launch(void* const* d_in, const int* in_sizes, int n_in,
                              void* d_out, int out_size, void* d_ws, size_t ws_size,
                              hipStream_t stream) {
    const float* q  = (const float*)d_in[0];
    const float* pr = (const float*)d_in[1];
    const float* W1 = (const float*)d_in[2];
    const float* b1 = (const float*)d_in[3];
    const float* W2 = (const float*)d_in[4];
    const float* b2 = (const float*)d_in[5];
    const float* W3 = (const float*)d_in[6];
    const float* b3 = (const float*)d_in[7];
    float* out = (float*)d_out;

    int ldsBytes = 32768 + 65536 + 2048;
    fused_kernel<<<NQ / 8, 512, ldsBytes, stream>>>(q, pr, W1, b1, W2, b2,
                                                    W3, b3, out);
}

// Round 14
// 22.403 us; speedup vs baseline: 2.4761x; 2.4761x over previous
//
#include <hip/hip_runtime.h>
#include <hip/hip_bf16.h>
#include <hip/hip_fp16.h>

// Problem constants
#define D1   128
#define NQ   2048
#define NP   256
#define H1   128
#define H2   64

typedef __attribute__((ext_vector_type(8))) _Float16 f16x8;
typedef __attribute__((ext_vector_type(2))) __fp16   h16x2;
typedef __attribute__((ext_vector_type(4))) float    f32x4;

// LDS layout (bytes). pf16 (raw p, f16) is consumed into regs in phase 1,
// then ALIASED as ph (projected p) -- barrier-separated.
#define L_PF   0          // [256][128] f16 swz   65536 B   (later ph [p][h])
#define L_W1Q  65536      // [128][128] f16 swz   32768 B
#define L_W1P  98304      // [128][128] f16 swz   32768 B
#define L_W2   131072     // [ 64][128] f16 swz   16384 B
#define L_QF   147456     // [  8][128] f16 swz    2048 B
#define L_QH   149504     // [  8][128] f16 lin    2048 B
#define LDS_TOTAL 151552

static __device__ __forceinline__ f16x8 cvt8(float4 a, float4 b) {
    f16x8 f;
    f[0] = (_Float16)a.x; f[1] = (_Float16)a.y;
    f[2] = (_Float16)a.z; f[3] = (_Float16)a.w;
    f[4] = (_Float16)b.x; f[5] = (_Float16)b.y;
    f[6] = (_Float16)b.z; f[7] = (_Float16)b.w;
    return f;
}
static __device__ __forceinline__ float sqsum8(f16x8 v, float acc) {
    union { f16x8 f; h16x2 h[4]; } u; u.f = v;
    acc = __builtin_amdgcn_fdot2(u.h[0], u.h[0], acc, false);
    acc = __builtin_amdgcn_fdot2(u.h[1], u.h[1], acc, false);
    acc = __builtin_amdgcn_fdot2(u.h[2], u.h[2], acc, false);
    acc = __builtin_amdgcn_fdot2(u.h[3], u.h[3], acc, false);
    return acc;
}
// 16B fragment read from a 256B-row f16 LDS array, XOR-swizzled
#define FRAG(base, row, ks) \
    (*(const f16x8*)((base) + ((((row) * 256 + (ks) * 64 + g * 16)) ^ (((row) & 7) << 4))))

// ---------------------------------------------------------------------------
// ONE kernel, 512 threads, grid 256 (1 block/CU), block = 8 q x 256 p.
// Wave w: p-range (w&3)*64, q-half & h-tile-half (w>>2).
// Phase 0: COALESCED staging (32B/thread bursts) of p, W1(q&p halves), W2,
//   q-tile into f16 LDS (fixes R13's 36MB scattered cold fetch).
// Phase 1: frag loads from LDS; q-proj -> qh_s; dist -> bse regs;
//   p-proj -> ph (aliases pf16). Phase 2: R12 main loop + epilogue.
// ---------------------------------------------------------------------------
__global__ void __launch_bounds__(512, 2)
fused_kernel(const float* __restrict__ q, const float* __restrict__ p,
             const float* __restrict__ W1, const float* __restrict__ b1,
             const float* __restrict__ W2, const float* __restrict__ b2,
             const float* __restrict__ w3, const float* __restrict__ b3,
             float* __restrict__ out) {
    extern __shared__ char lds[];
    char* pf_s  = lds + L_PF;
    char* w1q_s = lds + L_W1Q;
    char* w1p_s = lds + L_W1P;
    char* w2_s  = lds + L_W2;
    char* qf_s  = lds + L_QF;
    char* qh_s  = lds + L_QH;

    int tid = threadIdx.x, lane = tid & 63, w = tid >> 6;   // w 0..7
    int lo = lane & 15, g = lane >> 4;
    int wp = w & 3, qh2 = w >> 2;
    int q0 = blockIdx.x * 8;

    // ---------------- phase 0: coalesced staging ----------------
    #pragma unroll
    for (int it = 0; it < 8; ++it) {        // p: [256][128] f32, 32768 f32
        int j8 = (it * 512 + tid) * 8;
        int row = j8 >> 7;
        const float* src = p + j8;
        *(f16x8*)(pf_s + ((j8 * 2) ^ ((row & 7) << 4))) =
            cvt8(*(const float4*)src, *(const float4*)(src + 4));
    }
    #pragma unroll
    for (int it = 0; it < 8; ++it) {        // W1: [128][256] f32, split halves
        int j8 = (it * 512 + tid) * 8;
        int row = j8 >> 8, col = j8 & 255;
        const float* src = W1 + j8;
        f16x8 v = cvt8(*(const float4*)src, *(const float4*)(src + 4));
        char* base = (col < 128) ? w1q_s : w1p_s;
        *(f16x8*)(base + ((row * 256 + (col & 127) * 2) ^ ((row & 7) << 4))) = v;
    }
    #pragma unroll
    for (int it = 0; it < 2; ++it) {        // W2: [64][128] f32, 8192 f32
        int j8 = (it * 512 + tid) * 8;
        int row = j8 >> 7;
        const float* src = W2 + j8;
        *(f16x8*)(w2_s + ((j8 * 2) ^ ((row & 7) << 4))) =
            cvt8(*(const float4*)src, *(const float4*)(src + 4));
    }
    if (tid < 128) {                        // q rows q0..q0+7: 1024 f32
        int j8 = tid * 8;
        int row = j8 >> 7;
        const float* src = q + q0 * D1 + j8;
        *(f16x8*)(qf_s + ((j8 * 2) ^ ((row & 7) << 4))) =
            cvt8(*(const float4*)src, *(const float4*)(src + 4));
    }
    __syncthreads();                        // all staged

    // ---------------- phase 1a: fragment loads from LDS ----------------
    f16x8 Praw[4][4];                       // own 64 p rows as B-frags
    float psq[4];
    #pragma unroll
    for (int n = 0; n < 4; ++n) {
        int prow = wp * 64 + n * 16 + lo;
        psq[n] = 0.f;
        #pragma unroll
        for (int ks = 0; ks < 4; ++ks) {
            Praw[n][ks] = FRAG(pf_s, prow, ks);
            psq[n] = sqsum8(Praw[n][ks], psq[n]);
        }
        psq[n] += __shfl_xor(psq[n], 16);
        psq[n] += __shfl_xor(psq[n], 32);   // pn[prow] on every lane
    }
    f16x8 Adist[4];                         // q rows qh2*4+(lo&3), dup across g
    float asq = 0.f;
    {
        int qrow = qh2 * 4 + (lo & 3);
        #pragma unroll
        for (int ks = 0; ks < 4; ++ks) {
            Adist[ks] = FRAG(qf_s, qrow, ks);
            asq = sqsum8(Adist[ks], asq);
        }
        asq += __shfl_xor(asq, 16);
        asq += __shfl_xor(asq, 32);         // qn[qrow] on every lane
    }
    f16x8 Aq[4], Bq[4];                     // q-proj operands
    {
        int hrow = w * 16 + lo, qrow2 = lo & 7;
        #pragma unroll
        for (int ks = 0; ks < 4; ++ks) {
            Aq[ks] = FRAG(w1q_s, hrow, ks);
            Bq[ks] = FRAG(qf_s, qrow2, ks);
        }
    }
    const f32x4 Zv = (f32x4){0.f, 0.f, 0.f, 0.f};
    const f16x8 zz = {};
    const h16x2 z2 = {};
    float4 b1v = *(const float4*)(b1 + w * 16 + g * 4);
    __syncthreads();                        // pf_s reads done -> may overwrite

    // ---------------- phase 1b: q-proj, dist, p-proj ----------------
    {   // q-proj: D[h = w*16+g*4+r][q = lo], write rows lo<8, b1 folded
        f32x4 Cq = Zv;
        #pragma unroll
        for (int ks = 0; ks < 4; ++ks)
            Cq = __builtin_amdgcn_mfma_f32_16x16x32_f16(Aq[ks], Bq[ks], Cq, 0, 0, 0);
        if (lo < 8) {
            union { h16x2 h[2]; uint2 v; } pk;
            pk.h[0] = __builtin_amdgcn_cvt_pkrtz(Cq[0] + b1v.x, Cq[1] + b1v.y);
            pk.h[1] = __builtin_amdgcn_cvt_pkrtz(Cq[2] + b1v.z, Cq[3] + b1v.w);
            *(uint2*)(qh_s + lo * 256 + w * 32 + g * 8) = pk.v;
        }
    }
    float bse[4];
    {   // dist: D[q][p]; lane's own p -> frag n=g (R10 extraction)
        f32x4 Cd[4];
        #pragma unroll
        for (int n = 0; n < 4; ++n) {
            Cd[n] = Zv;
            #pragma unroll
            for (int ks = 0; ks < 4; ++ks)
                Cd[n] = __builtin_amdgcn_mfma_f32_16x16x32_f16(Adist[ks], Praw[n][ks], Cd[n], 0, 0, 0);
        }
        float pnm = (g == 0) ? psq[0] : (g == 1) ? psq[1] : (g == 2) ? psq[2] : psq[3];
        #pragma unroll
        for (int qq = 0; qq < 4; ++qq) {
            float qn = __shfl(asq, qq);
            float dg = (g == 0) ? Cd[0][qq] : (g == 1) ? Cd[1][qq]
                     : (g == 2) ? Cd[2][qq] : Cd[3][qq];
            bse[qq] = fmaxf(qn + pnm - 2.f * dg, 0.f);
        }
    }
    // p-proj: wave covers h-tiles qh2*4..+3 x own 4 p-tiles; write ph (=pf_s)
    #pragma unroll
    for (int hp = 0; hp < 2; ++hp) {
        f16x8 Ap[2][4];
        #pragma unroll
        for (int ht = 0; ht < 2; ++ht) {
            int h = (qh2 * 4 + hp * 2 + ht) * 16 + lo;
            #pragma unroll
            for (int ks = 0; ks < 4; ++ks)
                Ap[ht][ks] = FRAG(w1p_s, h, ks);
        }
        #pragma unroll
        for (int n = 0; n < 4; ++n) {
            f32x4 Cp0 = Zv, Cp1 = Zv;
            #pragma unroll
            for (int ks = 0; ks < 4; ++ks) {
                Cp0 = __builtin_amdgcn_mfma_f32_16x16x32_f16(Ap[0][ks], Praw[n][ks], Cp0, 0, 0, 0);
                Cp1 = __builtin_amdgcn_mfma_f32_16x16x32_f16(Ap[1][ks], Praw[n][ks], Cp1, 0, 0, 0);
            }
            int pp = wp * 64 + n * 16 + lo;
            #pragma unroll
            for (int ht = 0; ht < 2; ++ht) {
                f32x4 Cp = ht ? Cp1 : Cp0;
                int h0 = (qh2 * 4 + hp * 2 + ht) * 16 + g * 4;
                union { h16x2 h[2]; uint2 v; } pk;
                pk.h[0] = __builtin_amdgcn_cvt_pkrtz(Cp[0], Cp[1]);
                pk.h[1] = __builtin_amdgcn_cvt_pkrtz(Cp[2], Cp[3]);
                *(uint2*)(pf_s + ((pp * 256 + h0 * 2) ^ ((pp & 7) << 4))) = pk.v;
            }
        }
    }
    __syncthreads();                        // ph, qh ready

    // ---------------- phase 2: main MLP loop (R12 body) ----------------
    f16x8 P[4][4];
    #pragma unroll
    for (int n = 0; n < 4; ++n)
        #pragma unroll
        for (int ks = 0; ks < 4; ++ks) {
            int pp = wp * 64 + n * 16 + lo;
            P[n][ks] = FRAG(pf_s, pp, ks);
            asm volatile("" : "+v"(P[n][ks]));
        }
    f16x8 Af[4][4];
    #pragma unroll
    for (int m = 0; m < 4; ++m)
        #pragma unroll
        for (int ks = 0; ks < 4; ++ks) {
            Af[m][ks] = FRAG(w2_s, m * 16 + lo, ks);
            asm volatile("" : "+v"(Af[m][ks]));
        }

    h16x2 b2p[4][2], w3p[4][2];
    #pragma unroll
    for (int m = 0; m < 4; ++m) {
        float4 bb = *(const float4*)(b2 + m * 16 + g * 4);
        float4 ww = *(const float4*)(w3 + m * 16 + g * 4);
        b2p[m][0] = __builtin_amdgcn_cvt_pkrtz(bb.x, bb.y);
        b2p[m][1] = __builtin_amdgcn_cvt_pkrtz(bb.z, bb.w);
        w3p[m][0] = __builtin_amdgcn_cvt_pkrtz(ww.x, ww.y);
        w3p[m][1] = __builtin_amdgcn_cvt_pkrtz(ww.z, ww.w);
    }
    float b3v = b3[0];
    int pmine = wp * 64 + lane;
    int qb = qh2 * 4;

    f16x8 qkr[2][4];
    #pragma unroll
    for (int ks = 0; ks < 4; ++ks)
        qkr[0][ks] = *(const f16x8*)(qh_s + qb * 256 + ks * 64 + g * 16);

    #pragma unroll
    for (int qq = 0; qq < 4; ++qq) {
        float zp[4];
        #pragma unroll
        for (int hh = 0; hh < 2; ++hh) {
            f32x4 C[4][2];
            #pragma unroll
            for (int ks = 0; ks < 4; ++ks) {
                f16x8 B0 = __builtin_elementwise_max(P[2 * hh + 0][ks] + qkr[qq & 1][ks], zz);
                f16x8 B1 = __builtin_elementwise_max(P[2 * hh + 1][ks] + qkr[qq & 1][ks], zz);
                #pragma unroll
                for (int m = 0; m < 4; ++m) {
                    if (ks == 0) {
                        C[m][0] = __builtin_amdgcn_mfma_f32_16x16x32_f16(Af[m][0], B0, Zv, 0, 0, 0);
                        C[m][1] = __builtin_amdgcn_mfma_f32_16x16x32_f16(Af[m][0], B1, Zv, 0, 0, 0);
                    } else {
                        C[m][0] = __builtin_amdgcn_mfma_f32_16x16x32_f16(Af[m][ks], B0, C[m][0], 0, 0, 0);
                        C[m][1] = __builtin_amdgcn_mfma_f32_16x16x32_f16(Af[m][ks], B1, C[m][1], 0, 0, 0);
                    }
                }
            }
            if (hh == 0 && qq + 1 < 4) {
                #pragma unroll
                for (int ks = 0; ks < 4; ++ks)
                    qkr[(qq + 1) & 1][ks] =
                        *(const f16x8*)(qh_s + (qb + qq + 1) * 256 + ks * 64 + g * 16);
            }
            #pragma unroll
            for (int n2 = 0; n2 < 2; ++n2) {
                float sA = 0.f, sB = 0.f;
                #pragma unroll
                for (int m = 0; m < 4; ++m) {
                    h16x2 c01 = __builtin_amdgcn_cvt_pkrtz(C[m][n2][0], C[m][n2][1]);
                    h16x2 c23 = __builtin_amdgcn_cvt_pkrtz(C[m][n2][2], C[m][n2][3]);
                    h16x2 h01 = __builtin_elementwise_max(c01 + b2p[m][0], z2);
                    h16x2 h23 = __builtin_elementwise_max(c23 + b2p[m][1], z2);
                    sA = __builtin_amdgcn_fdot2(h01, w3p[m][0], sA, false);
                    sB = __builtin_amdgcn_fdot2(h23, w3p[m][1], sB, false);
                }
                zp[2 * hh + n2] = sA + sB;
            }
        }
        float sh[4];
        #pragma unroll
        for (int i = 0; i < 4; ++i) sh[i] = __shfl_xor(zp[i], 16);
        #pragma unroll
        for (int i = 0; i < 4; ++i) zp[i] += sh[i];
        #pragma unroll
        for (int i = 0; i < 4; ++i) sh[i] = __shfl_xor(zp[i], 32);
        #pragma unroll
        for (int i = 0; i < 4; ++i) zp[i] += sh[i];

        float z = (g == 0) ? zp[0] : (g == 1) ? zp[1] : (g == 2) ? zp[2] : zp[3];
        z += b3v;
        float sp = fmaxf(z, 0.f) + __logf(1.f + __expf(-fabsf(z)));
        out[(q0 + qb + qq) * NP + pmine] = bse[qq] * (1.f + sp);   // cw ~= alpha
    }
}

extern "C" void kernel_launch(void* const* d_in, const int* in_sizes, int n_in,
                              void* d_out, int out_size, void* d_ws, size_t ws_size,
                              hipStream_t stream) {
    const float* q  = (const float*)d_in[0];
    const float* pr = (const float*)d_in[1];
    const float* W1 = (const float*)d_in[2];
    const float* b1 = (const float*)d_in[3];
    const float* W2 = (const float*)d_in[4];
    const float* b2 = (const float*)d_in[5];
    const float* W3 = (const float*)d_in[6];
    const float* b3 = (const float*)d_in[7];
    float* out = (float*)d_out;

    fused_kernel<<<NQ / 8, 512, LDS_TOTAL, stream>>>(q, pr, W1, b1, W2, b2,
                                                     W3, b3, out);
}